// Round 1
// baseline (8660.686 us; speedup 1.0000x reference)
//
#include <hip/hip_runtime.h>

// k-means (Lloyd), N=500000 D=64 K=256 ITERS=10, fp32.
// Round 0: fused assign+LDS-accumulate kernel + finalize kernel.

#define D 64
#define K 256
#define KT 16          // centroid tile (accumulators per point)
#define GRID 512       // 2 blocks/CU
#define BLOCK 256
#define ITERS 10

// ---------------------------------------------------------------------------
// init: centroids0 = x[init_idx], csq[k] = ||c_k||^2
// grid = K blocks, block = 64 threads (one wave per centroid row)
__global__ void init_gather(const float* __restrict__ x,
                            const int* __restrict__ idx,
                            float* __restrict__ cent,
                            float* __restrict__ csq) {
    int k = blockIdx.x;
    int d = threadIdx.x;
    float v = x[(size_t)idx[k] * D + d];
    cent[k * D + d] = v;
    float s = v * v;
    #pragma unroll
    for (int off = 32; off > 0; off >>= 1) s += __shfl_down(s, off);
    if (d == 0) csq[k] = s;
}

// ---------------------------------------------------------------------------
// fused assignment + accumulation.
// gsums layout: [D][K] (matches LDS), gcounts: [K]
__global__ __launch_bounds__(BLOCK, 2) void assign_accum(
        const float* __restrict__ x,
        const float* __restrict__ cent,
        const float* __restrict__ csq,
        float* __restrict__ gsums,
        float* __restrict__ gcounts,
        int N, int ppb) {
    __shared__ float lsums[D * K];   // 64 KB, [d][k]
    __shared__ float lcounts[K];

    for (int i = threadIdx.x; i < D * K; i += BLOCK) lsums[i] = 0.0f;
    for (int i = threadIdx.x; i < K; i += BLOCK) lcounts[i] = 0.0f;
    __syncthreads();

    int base = blockIdx.x * ppb;
    int lim = base + ppb;
    if (lim > N) lim = N;

    #pragma unroll 1
    for (int i = base + (int)threadIdx.x; i < lim; i += BLOCK) {
        // ---- load point into registers (16 x float4) ----
        float xv[D];
        const float4* xp = (const float4*)(x + (size_t)i * D);
        #pragma unroll
        for (int q = 0; q < D / 4; ++q) {
            float4 v = xp[q];
            xv[4 * q + 0] = v.x; xv[4 * q + 1] = v.y;
            xv[4 * q + 2] = v.z; xv[4 * q + 3] = v.w;
        }
        float xsq = 0.0f;
        #pragma unroll
        for (int d = 0; d < D; ++d) xsq += xv[d] * xv[d];

        float best = 3.4e38f;
        int bestk = 0;

        #pragma unroll 1
        for (int kt = 0; kt < K; kt += KT) {
            float acc[KT];
            #pragma unroll
            for (int j = 0; j < KT; ++j) acc[j] = 0.0f;
            // wave-uniform centroid reads -> scalar loads; 16 indep FMA chains
            #pragma unroll
            for (int j = 0; j < KT; ++j) {
                const float* cr = cent + (kt + j) * D;
                #pragma unroll
                for (int d = 0; d < D; ++d) acc[j] += cr[d] * xv[d];
            }
            #pragma unroll
            for (int j = 0; j < KT; ++j) {
                float dist = xsq - 2.0f * acc[j] + csq[kt + j];
                if (dist < best) { best = dist; bestk = kt + j; }
            }
        }

        // ---- accumulate into LDS partials ----
        #pragma unroll
        for (int d = 0; d < D; ++d) atomicAdd(&lsums[d * K + bestk], xv[d]);
        atomicAdd(&lcounts[bestk], 1.0f);
    }

    __syncthreads();
    // ---- flush block partials to global with atomics ----
    for (int i = threadIdx.x; i < D * K; i += BLOCK) {
        float v = lsums[i];
        if (v != 0.0f) atomicAdd(&gsums[i], v);
    }
    for (int i = threadIdx.x; i < K; i += BLOCK) {
        float v = lcounts[i];
        if (v != 0.0f) atomicAdd(&gcounts[i], v);
    }
}

// ---------------------------------------------------------------------------
// finalize: new centroids + csq for next iter + re-zero accumulators.
// grid = K blocks, block = 64 threads (one wave per centroid)
__global__ void finalize(float* __restrict__ cent,
                         float* __restrict__ gsums,
                         float* __restrict__ gcounts,
                         float* __restrict__ csq) {
    int k = blockIdx.x;
    int d = threadIdx.x;
    float cnt = gcounts[k];
    float s = gsums[d * K + k];          // gsums is [D][K]
    float oldc = cent[k * D + d];
    float nc = (cnt > 0.0f) ? (s / cnt) : oldc;
    cent[k * D + d] = nc;
    float v = nc * nc;
    #pragma unroll
    for (int off = 32; off > 0; off >>= 1) v += __shfl_down(v, off);
    if (d == 0) csq[k] = v;
    // re-zero accumulators for the next iteration
    gsums[d * K + k] = 0.0f;
    if (d == 0) gcounts[k] = 0.0f;
}

// ---------------------------------------------------------------------------
extern "C" void kernel_launch(void* const* d_in, const int* in_sizes, int n_in,
                              void* d_out, int out_size, void* d_ws, size_t ws_size,
                              hipStream_t stream) {
    const float* x = (const float*)d_in[0];
    const int* init_idx = (const int*)d_in[1];
    // n_clusters / n_iters are fixed by the problem (K=256, ITERS=10)

    int N = in_sizes[0] / D;

    float* cent = (float*)d_out;            // K*D working + output buffer
    float* gsums = (float*)d_ws;            // K*D   ([D][K] layout)
    float* gcounts = gsums + K * D;         // K
    float* csq = gcounts + K;               // K

    // zero the accumulators once; finalize re-zeros after each iteration
    hipMemsetAsync(d_ws, 0, (size_t)(K * D + K) * sizeof(float), stream);

    init_gather<<<dim3(K), dim3(64), 0, stream>>>(x, init_idx, cent, csq);

    int ppb = (N + GRID - 1) / GRID;
    for (int it = 0; it < ITERS; ++it) {
        assign_accum<<<dim3(GRID), dim3(BLOCK), 0, stream>>>(
            x, cent, csq, gsums, gcounts, N, ppb);
        finalize<<<dim3(K), dim3(64), 0, stream>>>(cent, gsums, gcounts, csq);
    }
}

// Round 3
// 4418.981 us; speedup vs baseline: 1.9599x; 1.9599x over previous
//
#include <hip/hip_runtime.h>

// k-means (Lloyd), N=500000 D=64 K=256 ITERS=10, fp32.
// Round 2: round-1 design with the double-count bug fixed (per-block range
// clamped to ppb) and the reference distance formula restored
// (dist = x^2 - 2 x.c + c^2, proven-passing numerics from round 0).

#define D 64
#define K 256
#define KT 8            // centroid tile (accumulators per point)
#define BLOCK 512       // 8 waves
#define NB_MAX 256      // one block per CU
#define ITERS 10
#define PART_STRIDE (D * K + K)          // floats per block partial (sums+counts)
#define SMEM_BYTES ((D * K + K + D * K + K) * 4)   // cent + csq + sums + cnt

// ---------------------------------------------------------------------------
// init: centroids0 = x[init_idx], csq[k] = ||c_k||^2
__global__ void init_gather(const float* __restrict__ x,
                            const int* __restrict__ idx,
                            float* __restrict__ cent,
                            float* __restrict__ csq) {
    int k = blockIdx.x;
    int d = threadIdx.x;
    float v = x[(size_t)idx[k] * D + d];
    cent[k * D + d] = v;
    float s = v * v;
    #pragma unroll
    for (int off = 32; off > 0; off >>= 1) s += __shfl_down(s, off);
    if (d == 0) csq[k] = s;
}

// ---------------------------------------------------------------------------
// fused assignment + accumulation. parts[b] = [D*K sums ([d][k]) | K counts]
__global__ __launch_bounds__(BLOCK, 2) void assign_fused(
        const float* __restrict__ x,
        const float* __restrict__ cent,
        const float* __restrict__ csq,
        float* __restrict__ parts,
        int N, int ppb) {
    extern __shared__ float smem[];
    float* s_cent = smem;                    // [K][D] 16384
    float* s_csq  = s_cent + D * K;          // K
    float* s_sums = s_csq + K;               // [D][K] 16384
    float* s_cnt  = s_sums + D * K;          // K

    const int tid = threadIdx.x;

    // stage centroids + csq, zero partials (float4 strided copies)
    {
        const float4* c4 = (const float4*)cent;
        float4* sc4 = (float4*)s_cent;
        #pragma unroll 1
        for (int i = tid; i < (D * K) / 4; i += BLOCK) sc4[i] = c4[i];
        if (tid < K / 4) ((float4*)s_csq)[tid] = ((const float4*)csq)[tid];
        float4 z = {0.f, 0.f, 0.f, 0.f};
        float4* ss4 = (float4*)s_sums;
        #pragma unroll 1
        for (int i = tid; i < (D * K) / 4; i += BLOCK) ss4[i] = z;
        if (tid >= K / 4 && tid < K / 2) ((float4*)s_cnt)[tid - K / 4] = z;
    }
    __syncthreads();

    const int base = blockIdx.x * ppb;
    int lim = base + ppb;
    if (lim > N) lim = N;
    const int rounds = (ppb + 2 * BLOCK - 1) / (2 * BLOCK);

    #pragma unroll 1
    for (int r = 0; r < rounds; ++r) {
        int p0 = base + r * 2 * BLOCK + tid;
        int p1 = p0 + BLOCK;
        bool v0 = p0 < lim, v1 = p1 < lim;
        int a0 = v0 ? p0 : base;
        int a1 = v1 ? p1 : base;

        float xv0[D], xv1[D];
        {
            const float4* xp0 = (const float4*)(x + (size_t)a0 * D);
            const float4* xp1 = (const float4*)(x + (size_t)a1 * D);
            #pragma unroll
            for (int q = 0; q < D / 4; ++q) {
                float4 u = xp0[q];
                xv0[4 * q + 0] = u.x; xv0[4 * q + 1] = u.y;
                xv0[4 * q + 2] = u.z; xv0[4 * q + 3] = u.w;
                float4 w = xp1[q];
                xv1[4 * q + 0] = w.x; xv1[4 * q + 1] = w.y;
                xv1[4 * q + 2] = w.z; xv1[4 * q + 3] = w.w;
            }
        }
        float xsq0 = 0.f, xsq1 = 0.f;
        #pragma unroll
        for (int d = 0; d < D; ++d) { xsq0 += xv0[d] * xv0[d]; xsq1 += xv1[d] * xv1[d]; }

        float best0 = 3.4e38f, best1 = 3.4e38f;
        int bk0 = 0, bk1 = 0;

        #pragma unroll 1
        for (int kt = 0; kt < K; kt += KT) {
            float acc0[KT], acc1[KT];
            #pragma unroll
            for (int j = 0; j < KT; ++j) { acc0[j] = 0.f; acc1[j] = 0.f; }

            #pragma unroll
            for (int d4 = 0; d4 < D; d4 += 4) {
                #pragma unroll
                for (int j = 0; j < KT; ++j) {
                    float4 c = *(const float4*)&s_cent[(kt + j) * D + d4];
                    acc0[j] += c.x * xv0[d4 + 0];
                    acc0[j] += c.y * xv0[d4 + 1];
                    acc0[j] += c.z * xv0[d4 + 2];
                    acc0[j] += c.w * xv0[d4 + 3];
                    acc1[j] += c.x * xv1[d4 + 0];
                    acc1[j] += c.y * xv1[d4 + 1];
                    acc1[j] += c.z * xv1[d4 + 2];
                    acc1[j] += c.w * xv1[d4 + 3];
                }
            }
            #pragma unroll
            for (int j = 0; j < KT; ++j) {
                float d0 = xsq0 - 2.0f * acc0[j] + s_csq[kt + j];
                if (d0 < best0) { best0 = d0; bk0 = kt + j; }
                float d1 = xsq1 - 2.0f * acc1[j] + s_csq[kt + j];
                if (d1 < best1) { best1 = d1; bk1 = kt + j; }
            }
        }

        if (v0) {
            #pragma unroll
            for (int d = 0; d < D; ++d) atomicAdd(&s_sums[d * K + bk0], xv0[d]);
            atomicAdd(&s_cnt[bk0], 1.0f);
        }
        if (v1) {
            #pragma unroll
            for (int d = 0; d < D; ++d) atomicAdd(&s_sums[d * K + bk1], xv1[d]);
            atomicAdd(&s_cnt[bk1], 1.0f);
        }
    }

    __syncthreads();
    // non-atomic flush of this block's partials
    float* part = parts + (size_t)blockIdx.x * PART_STRIDE;
    float4* p4 = (float4*)part;
    const float4* ss4 = (const float4*)s_sums;
    #pragma unroll 1
    for (int i = tid; i < (D * K) / 4; i += BLOCK) p4[i] = ss4[i];
    if (tid < K / 4) p4[(D * K) / 4 + tid] = ((const float4*)s_cnt)[tid];
}

// ---------------------------------------------------------------------------
// reduce partials: gsums[j] = sum_b parts[b][j], j in [0, D*K+K)
__global__ void reduce_partials(const float* __restrict__ parts,
                                float* __restrict__ gsums, int nb) {
    int j = blockIdx.x * blockDim.x + threadIdx.x;
    if (j >= PART_STRIDE) return;
    float s = 0.f;
    #pragma unroll 4
    for (int b = 0; b < nb; ++b) s += parts[(size_t)b * PART_STRIDE + j];
    gsums[j] = s;
}

// ---------------------------------------------------------------------------
// finalize: new centroids + csq. gsums: [D*K sums ([d][k]) | K counts]
__global__ void finalize(float* __restrict__ cent,
                         const float* __restrict__ gsums,
                         float* __restrict__ csq) {
    int k = blockIdx.x;
    int d = threadIdx.x;
    float cnt = gsums[D * K + k];
    float s = gsums[d * K + k];
    float oldc = cent[k * D + d];
    float nc = (cnt > 0.0f) ? (s / cnt) : oldc;
    cent[k * D + d] = nc;
    float v = nc * nc;
    #pragma unroll
    for (int off = 32; off > 0; off >>= 1) v += __shfl_down(v, off);
    if (d == 0) csq[k] = v;
}

// ---------------------------------------------------------------------------
extern "C" void kernel_launch(void* const* d_in, const int* in_sizes, int n_in,
                              void* d_out, int out_size, void* d_ws, size_t ws_size,
                              hipStream_t stream) {
    const float* x = (const float*)d_in[0];
    const int* init_idx = (const int*)d_in[1];

    int N = in_sizes[0] / D;

    float* cent = (float*)d_out;            // K*D working + output buffer

    // ws layout: parts[nb][PART_STRIDE] | gsums[PART_STRIDE] | csq[K]
    size_t fixed = (size_t)(PART_STRIDE + K) * sizeof(float);
    int nb = NB_MAX;
    if (ws_size < fixed + (size_t)NB_MAX * PART_STRIDE * sizeof(float)) {
        size_t avail = (ws_size > fixed) ? (ws_size - fixed) : 0;
        nb = (int)(avail / (PART_STRIDE * sizeof(float)));
        if (nb < 1) nb = 1;   // (ws_size is expected to be ample; safety only)
    }
    float* parts = (float*)d_ws;
    float* gsums = parts + (size_t)nb * PART_STRIDE;
    float* csq = gsums + PART_STRIDE;

    // allow >64KB dynamic LDS
    hipFuncSetAttribute(reinterpret_cast<const void*>(assign_fused),
                        hipFuncAttributeMaxDynamicSharedMemorySize, SMEM_BYTES);

    init_gather<<<dim3(K), dim3(64), 0, stream>>>(x, init_idx, cent, csq);

    int ppb = (N + nb - 1) / nb;
    for (int it = 0; it < ITERS; ++it) {
        assign_fused<<<dim3(nb), dim3(BLOCK), SMEM_BYTES, stream>>>(
            x, cent, csq, parts, N, ppb);
        reduce_partials<<<dim3((PART_STRIDE + 255) / 256), dim3(256), 0, stream>>>(
            parts, gsums, nb);
        finalize<<<dim3(K), dim3(64), 0, stream>>>(cent, gsums, csq);
    }
}